// Round 14
// baseline (6113.982 us; speedup 1.0000x reference)
//
#include <hip/hip_runtime.h>
#include <math.h>

typedef _Float16 f16;
typedef __attribute__((ext_vector_type(8))) _Float16 f16x8;
typedef __attribute__((ext_vector_type(4))) _Float16 f16x4;
typedef __attribute__((ext_vector_type(4))) float f32x4;

namespace {
constexpr int B_ = 1024, T_ = 168, H_ = 512, K_ = 8, TAU_ = 24, U_ = 192;
}

__device__ __forceinline__ float sig_(float x) { return 1.0f / (1.0f + expf(-x)); }

// CPol aux bits (gfx940+): SC0=1, NT=2, SC1=16. Device scope = SC1.
template<int AUX>
__device__ __forceinline__ void gl16(const f16* g, char* l) {
    __builtin_amdgcn_global_load_lds((const __attribute__((address_space(1))) void*)g,
                                     (__attribute__((address_space(3))) void*)l, 16, 0, AUX);
}
// device-scope (LLC-coherent) 2-byte store
__device__ __forceinline__ void st_h_sc1(f16* p, f16 v) {
    unsigned int u = (unsigned int)__builtin_bit_cast(unsigned short, v);
    asm volatile("global_store_short %0, %1, off sc1" :: "v"(p), "v"(u) : "memory");
}
#define MFMA16 __builtin_amdgcn_mfma_f32_16x16x32_f16

struct PP {
    const f16 *xp, *w0p, *wsW;      // xp[t][B][64]; w0p[2048][64]; wsW: 7x[2048][512]
    const float* bsum;              // [4][2048]
    const f16* hzero;               // zeros [B][512]
    f16 *h0r, *h1r;                 // 8-deep rings of [B][512] slabs
    f16* h1dec;                     // 24 decoder h1 slabs [s][B][512]
    int *cnt0, *cnt1;               // [192][16] flag counters
};

// Persistent LSTM, SPLIT-CHAIN: 512 blocks = 2/CU (72KB LDS each). Even id2 =
// L0-chain block, odd = L1-chain block, each owning one (rt,jt) 64x32 tile for
// all 192 steps. Encoder runs L1(u) || L0(u+1) on sibling blocks (true stagger);
// sibling TLP hides each block's staging/drain/spin latency. h at device scope
// (sc1), weights default-cached, depth-3 LDS pipeline, fail-soft sticky spins.
extern "C" __global__ void __launch_bounds__(256, 2)
lstm_persist(PP P)
{
    extern __shared__ char lds[];   // 3 bufs x 24 KB = 72 KB
    const int tid = threadIdx.x;
    const int id2 = (blockIdx.x & 7) * 64 + (blockIdx.x >> 3);   // XCD-chunked
    const int wv  = id2 & 63;
    const int chain = wv & 1;            // 0 = L0-chain, 1 = L1-chain
    const int tt  = wv >> 1;             // 0..31
    const int rt  = tt & 15;
    const int jt  = (id2 >> 6) * 2 + (tt >> 4);   // 2 jt values per XCD
    const int row0 = rt * 64;
    const int j0   = jt * 32;

    const int lane = tid & 63, wid = tid >> 6;
    const int l16 = lane & 15, lq = lane >> 4;
    const int wr = wid >> 1, wc = wid & 1;
    const int sr = tid >> 3, sl = tid & 7;
    const long ksw = (long)((sl ^ (sr & 7)) << 3);

    auto wgf = [&](int q) {
        const int r = sr + 32 * q;
        return (long)(((r >> 4) & 3) * H_ + j0 + ((r >> 6) << 4) + (r & 15));
    };
    const long wgr0 = wgf(0), wgr1 = wgf(1), wgr2 = wgf(2), wgr3 = wgf(3);
    const long wgH0 = wgr0 * H_ + ksw, wgH1 = wgr1 * H_ + ksw;
    const long wgH2 = wgr2 * H_ + ksw, wgH3 = wgr3 * H_ + ksw;
    const long aH0k = (long)(row0 + sr) * H_ + ksw, aH1k = aH0k + 32 * H_;

    const int swz = (l16 & 7) << 4;
    const int ab0 = (wr * 32 + l16) * 128;
    const int ab1 = ab0 + 2048;
    const int wb0 = (wc * 64 + 0 * 16 + l16) * 128, wb1 = (wc * 64 + 1 * 16 + l16) * 128;
    const int wb2 = (wc * 64 + 2 * 16 + l16) * 128, wb3 = (wc * 64 + 3 * 16 + l16) * 128;

    const size_t WM  = (size_t)2048 * 512;
    const long   NBH = (long)B_ * H_;
    bool dead = false;              // tid 0 only

    auto waitf = [&](const int* p) {
        if (tid == 0 && !dead) {
            int tries = 0;
            while (__hip_atomic_load(p, __ATOMIC_RELAXED,
                                     __HIP_MEMORY_SCOPE_AGENT) < 16) {
                __builtin_amdgcn_s_sleep(1);
                if (++tries > (1 << 16)) { dead = true; break; }
            }
        }
        __syncthreads();
    };
    auto sig1 = [&](int* p) {
        asm volatile("s_waitcnt vmcnt(0)" ::: "memory");
        __syncthreads();
        if (tid == 0)
            __hip_atomic_fetch_add(p, 1, __ATOMIC_RELAXED, __HIP_MEMORY_SCOPE_AGENT);
    };

    auto computeChunk = [&](char* lb, f32x4 (&acc)[4][2]) {
        #pragma unroll
        for (int ks = 0; ks < 2; ++ks) {
            const int kb = ((ks * 64) + lq * 16) ^ swz;
            f16x8 ah0 = *(const f16x8*)(lb + ab0 + kb);
            f16x8 ah1 = *(const f16x8*)(lb + ab1 + kb);
            f16x8 w0 = *(const f16x8*)(lb + 8192 + wb0 + kb);
            f16x8 w1 = *(const f16x8*)(lb + 8192 + wb1 + kb);
            f16x8 w2 = *(const f16x8*)(lb + 8192 + wb2 + kb);
            f16x8 w3 = *(const f16x8*)(lb + 8192 + wb3 + kb);
            acc[0][0] = MFMA16(ah0, w0, acc[0][0], 0, 0, 0);
            acc[0][1] = MFMA16(ah1, w0, acc[0][1], 0, 0, 0);
            acc[1][0] = MFMA16(ah0, w1, acc[1][0], 0, 0, 0);
            acc[1][1] = MFMA16(ah1, w1, acc[1][1], 0, 0, 0);
            acc[2][0] = MFMA16(ah0, w2, acc[2][0], 0, 0, 0);
            acc[2][1] = MFMA16(ah1, w2, acc[2][1], 0, 0, 0);
            acc[3][0] = MFMA16(ah0, w3, acc[3][0], 0, 0, 0);
            acc[3][1] = MFMA16(ah1, w3, acc[3][1], 0, 0, 0);
        }
    };

    auto epiF = [&](const float* bg, float* cst, f16* hout, f32x4 (&a)[4][2]) {
        const int j = j0 + wc * 16 + l16;
        const float bg0 = bg[j], bg1 = bg[H_ + j];
        const float bg2 = bg[2 * H_ + j], bg3 = bg[3 * H_ + j];
        #pragma unroll
        for (int m = 0; m < 2; ++m)
            #pragma unroll
            for (int r = 0; r < 4; ++r) {
                const int ci = m * 4 + r;
                const int bb = row0 + wr * 32 + m * 16 + lq * 4 + r;
                const long base = (long)bb * H_ + j;
                const float pi = a[0][m][r] + bg0;
                const float pf = a[1][m][r] + bg1;
                const float pg = a[2][m][r] + bg2;
                const float po = a[3][m][r] + bg3;
                const float cn = sig_(pf) * cst[ci] + sig_(pi) * tanhf(pg);
                const float hn = sig_(po) * tanhf(cn);
                cst[ci] = cn;
                st_h_sc1(&hout[base], (f16)hn);
            }
    };

    float cst[8];
    #pragma unroll
    for (int i = 0; i < 8; ++i) cst[i] = 0.f;

    // ---- one cell, depth-3 pipeline, scratch-free staging ----
    auto runCell = [&](const f16* Ain, long lda, int ncIn, long Kw,
                       const f16* Wih, const f16* Hin, const f16* Whh,
                       const float* bg, f16* hout) {
        const long aA0 = (long)(row0 + sr) * lda + ksw;
        const long aA1 = aA0 + 32 * lda;
        const long wK0 = wgr0 * Kw + ksw, wK1 = wgr1 * Kw + ksw;
        const long wK2 = wgr2 * Kw + ksw, wK3 = wgr3 * Kw + ksw;
        const int NC = ncIn + 8;
        auto st = [&](int ci) {
            char* lb = lds + (ci % 3) * 24576;
            const bool inp = ci < ncIn;
            const long k0 = (long)(inp ? ci : ci - ncIn) << 6;
            const f16* Ap = inp ? Ain : Hin;
            const f16* Wp = inp ? Wih : Whh;
            gl16<16>(Ap + (inp ? aA0 : aH0k) + k0, lb + tid * 16);
            gl16<16>(Ap + (inp ? aA1 : aH1k) + k0, lb + 4096 + tid * 16);
            gl16<0>(Wp + (inp ? wK0 : wgH0) + k0, lb + 8192  + tid * 16);
            gl16<0>(Wp + (inp ? wK1 : wgH1) + k0, lb + 12288 + tid * 16);
            gl16<0>(Wp + (inp ? wK2 : wgH2) + k0, lb + 16384 + tid * 16);
            gl16<0>(Wp + (inp ? wK3 : wgH3) + k0, lb + 20480 + tid * 16);
        };
        f32x4 acc[4][2];
        #pragma unroll
        for (int nf = 0; nf < 4; ++nf)
            #pragma unroll
            for (int m = 0; m < 2; ++m)
                #pragma unroll
                for (int q = 0; q < 4; ++q) acc[nf][m][q] = 0.f;
        st(0); st(1); st(2);
        for (int i = 0; i < NC; ++i) {
            const int ahead = (NC - 1 - i) < 2 ? (NC - 1 - i) : 2;
            if      (ahead == 2) asm volatile("s_waitcnt vmcnt(12)" ::: "memory");
            else if (ahead == 1) asm volatile("s_waitcnt vmcnt(6)"  ::: "memory");
            else                 asm volatile("s_waitcnt vmcnt(0)"  ::: "memory");
            __builtin_amdgcn_s_barrier();
            computeChunk(lds + (i % 3) * 24576, acc);
            asm volatile("s_waitcnt lgkmcnt(0)" ::: "memory");
            __builtin_amdgcn_s_barrier();
            if (i + 3 < NC) st(i + 3);
        }
        epiF(bg, cst, hout, acc);
    };

    if (chain == 0) {
        // ================= L0-chain =================
        for (int u = 0; u < U_; ++u) {
            const bool dec = (u >= T_);
            if (u > 0) waitf(P.cnt0 + (u - 1) * 16 + rt);      // recurrent h0 peers
            if (dec)   waitf(P.cnt1 + (u - 1) * 16 + rt);      // A = h1(u-1)
            else if (u >= 8) waitf(P.cnt1 + (u - 8) * 16 + rt);// h0 ring overwrite guard
            const f16* h0prev = (u == 0) ? P.hzero : P.h0r + (long)((u - 1) & 7) * NBH;
            f16* h0out = P.h0r + (long)(u & 7) * NBH;
            if (dec) {
                const f16* h1prev = (u <= T_) ? P.h1r + (long)((u - 1) & 7) * NBH
                                              : P.h1dec + (long)(u - 1 - T_) * NBH;
                runCell(h1prev, H_, 8, H_, P.wsW + 3 * WM, h0prev,
                        P.wsW + 4 * WM, P.bsum + 4096, h0out);
            } else {
                runCell(P.xp + (long)u * B_ * 64, 64, 1, 64, P.w0p, h0prev,
                        P.wsW, P.bsum, h0out);
            }
            sig1(P.cnt0 + u * 16 + rt);
        }
    } else {
        // ================= L1-chain =================
        for (int u = 0; u < U_; ++u) {
            const bool dec = (u >= T_);
            waitf(P.cnt0 + u * 16 + rt);                       // A = h0(u), all cols
            if (u > 0) waitf(P.cnt1 + (u - 1) * 16 + rt);      // recurrent h1 peers
            const f16* h1prev = (u == 0) ? P.hzero
                              : (u <= T_ ? P.h1r + (long)((u - 1) & 7) * NBH
                                         : P.h1dec + (long)(u - 1 - T_) * NBH);
            f16* h1out = (u < T_) ? P.h1r + (long)(u & 7) * NBH
                                  : P.h1dec + (long)(u - T_) * NBH;
            runCell(P.h0r + (long)(u & 7) * NBH, H_, 8, H_,
                    dec ? P.wsW + 5 * WM : P.wsW + 1 * WM, h1prev,
                    dec ? P.wsW + 6 * WM : P.wsW + 2 * WM,
                    P.bsum + (dec ? 6144 : 2048), h1out);
            sig1(P.cnt1 + u * 16 + rt);
        }
    }
}

// x[B][T][32] fp32 -> xp[t][B][64] fp16 zero-padded
extern "C" __global__ void __launch_bounds__(256)
padx_kernel(const float* __restrict__ x, f16* __restrict__ xp)
{
    const int idx = blockIdx.x * 256 + threadIdx.x;     // t*B + b
    const int t = idx >> 10, b = idx & 1023;
    const float* src = x + ((long)b * T_ + t) * 32;
    f16* dst = xp + (long)idx * 64;
    #pragma unroll
    for (int q = 0; q < 8; ++q) {
        float4 v = *(const float4*)&src[q * 4];
        *(f16x4*)&dst[q * 4] = (f16x4){(f16)v.x, (f16)v.y, (f16)v.z, (f16)v.w};
    }
    #pragma unroll
    for (int q = 8; q < 16; ++q) *(f16x4*)&dst[q * 4] = (f16x4){0, 0, 0, 0};
}

// eWih0 [2048][32] fp32 -> [2048][64] fp16 zero-padded
extern "C" __global__ void __launch_bounds__(256)
padw_kernel(const float* __restrict__ w, f16* __restrict__ dst)
{
    const int idx = blockIdx.x * 256 + threadIdx.x;
    const int row = idx >> 4, k4 = idx & 15;
    f16x4 hv = (f16x4){0, 0, 0, 0};
    if (k4 < 8) {
        float4 v = *(const float4*)&w[(long)row * 32 + k4 * 4];
        hv = (f16x4){(f16)v.x, (f16)v.y, (f16)v.z, (f16)v.w};
    }
    *(f16x4*)&dst[(long)row * 64 + k4 * 4] = hv;
}

// 7 x [2048][512] fp32 -> fp16 contiguous
extern "C" __global__ void __launch_bounds__(256)
wcvt_kernel(const float* s0, const float* s1, const float* s2, const float* s3,
            const float* s4, const float* s5, const float* s6, f16* dst)
{
    const int i = blockIdx.x * 256 + threadIdx.x;
    if (i >= 7 * 262144) return;
    const int m = i >> 18, off = i & 262143;
    const float* s = m == 0 ? s0 : m == 1 ? s1 : m == 2 ? s2 : m == 3 ? s3
                   : m == 4 ? s4 : m == 5 ? s5 : s6;
    float4 v = ((const float4*)s)[off];
    *(f16x4*)&dst[(long)m * 1048576 + (long)off * 4] =
        (f16x4){(f16)v.x, (f16)v.y, (f16)v.z, (f16)v.w};
}

extern "C" __global__ void __launch_bounds__(256)
bias_kernel(const float* a0, const float* b0, const float* a1, const float* b1,
            const float* a2, const float* b2, const float* a3, const float* b3,
            float* out)   // [4][2048]: enc0, enc1, dec0, dec1
{
    const int i = blockIdx.x * 256 + threadIdx.x;
    const int l = i >> 11, k = i & 2047;
    const float* pa = l == 0 ? a0 : l == 1 ? a1 : l == 2 ? a2 : a3;
    const float* pb = l == 0 ? b0 : l == 1 ? b1 : l == 2 ? b2 : b3;
    out[i] = pa[k] + pb[k];
}

extern "C" __global__ void __launch_bounds__(256)
zero16(uint4* p, int n)
{
    for (int i = blockIdx.x * 256 + threadIdx.x; i < n; i += gridDim.x * 256)
        p[i] = make_uint4(0, 0, 0, 0);
}

// mu / sigma heads for all 24 decoder steps from h1 slabs
extern "C" __global__ void __launch_bounds__(256)
head_all(const f16* __restrict__ h1dec,
         const float* __restrict__ W1, const float* __restrict__ b1,
         const float* __restrict__ W2, const float* __restrict__ b2,
         float* __restrict__ out)
{
    const int blk = blockIdx.x;                 // 24 * 64
    const int s = blk >> 6;
    const int idx = (blk & 63) * 256 + threadIdx.x;     // 0..16383
    const int b = idx >> 4, rr = idx & 15, k = rr & 7, which = rr >> 3;
    const float* w  = (which ? W2 : W1) + (long)k * H_;
    const f16*   hp = h1dec + ((long)s * B_ + b) * H_;
    float sum = 0.f;
    for (int d = 0; d < H_; d += 8) {
        f16x8  hv = *(const f16x8*)&hp[d];
        float4 w0 = *(const float4*)&w[d];
        float4 w1 = *(const float4*)&w[d + 4];
        sum = fmaf((float)hv[0], w0.x, sum);
        sum = fmaf((float)hv[1], w0.y, sum);
        sum = fmaf((float)hv[2], w0.z, sum);
        sum = fmaf((float)hv[3], w0.w, sum);
        sum = fmaf((float)hv[4], w1.x, sum);
        sum = fmaf((float)hv[5], w1.y, sum);
        sum = fmaf((float)hv[6], w1.z, sum);
        sum = fmaf((float)hv[7], w1.w, sum);
    }
    const long o = ((long)b * TAU_ + s) * K_ + k;
    if (which == 0) {
        out[o] = sum + b1[k];
    } else {
        float z  = 2.0f * (sum + b2[k]);
        float sp = fmaxf(z, 0.0f) + log1pf(expf(-fabsf(z)));
        out[(long)B_ * TAU_ * K_ + o] = 0.5f * sp;
    }
}

extern "C" void kernel_launch(void* const* d_in, const int* in_sizes, int n_in,
                              void* d_out, int out_size, void* d_ws, size_t ws_size,
                              hipStream_t stream)
{
    (void)in_sizes; (void)n_in; (void)out_size; (void)ws_size;

    const float* x     = (const float*)d_in[0];
    const float* eWih0 = (const float*)d_in[1];
    const float* eWhh0 = (const float*)d_in[2];
    const float* ebih0 = (const float*)d_in[3];
    const float* ebhh0 = (const float*)d_in[4];
    const float* eWih1 = (const float*)d_in[5];
    const float* eWhh1 = (const float*)d_in[6];
    const float* ebih1 = (const float*)d_in[7];
    const float* ebhh1 = (const float*)d_in[8];
    const float* dWih0 = (const float*)d_in[9];
    const float* dWhh0 = (const float*)d_in[10];
    const float* dbih0 = (const float*)d_in[11];
    const float* dbhh0 = (const float*)d_in[12];
    const float* dWih1 = (const float*)d_in[13];
    const float* dWhh1 = (const float*)d_in[14];
    const float* dbih1 = (const float*)d_in[15];
    const float* dbhh1 = (const float*)d_in[16];
    const float* W1    = (const float*)d_in[17];
    const float* b1    = (const float*)d_in[18];
    const float* W2    = (const float*)d_in[19];
    const float* b2    = (const float*)d_in[20];
    float* out = (float*)d_out;

    (void)hipFuncSetAttribute((const void*)lstm_persist,
                              hipFuncAttributeMaxDynamicSharedMemorySize, 73728);

    char* wsp = (char*)d_ws;
    auto take = [&](size_t n) { void* p = (void*)wsp; wsp += n; return p; };

    f16* xp    = (f16*)take((size_t)T_ * B_ * 64 * 2);
    f16* w0p   = (f16*)take((size_t)2048 * 64 * 2);
    f16* wsW   = (f16*)take((size_t)7 * 2048 * 512 * 2);
    float* bsum = (float*)take((size_t)4 * 2048 * 4);
    f16* h1dec = (f16*)take((size_t)TAU_ * B_ * H_ * 2);
    f16* h0r   = (f16*)take((size_t)8 * B_ * H_ * 2);
    f16* h1r   = (f16*)take((size_t)8 * B_ * H_ * 2);

    char* zstart = wsp;
    int* cnt0  = (int*)take((size_t)U_ * 16 * 4);
    int* cnt1  = (int*)take((size_t)U_ * 16 * 4);
    f16* hzero = (f16*)take((size_t)B_ * H_ * 2);
    const size_t zeroBytes = (size_t)(wsp - zstart);

    const dim3 blk(256);

    padx_kernel<<<dim3(T_ * B_ / 256), blk, 0, stream>>>(x, xp);
    padw_kernel<<<dim3(128), blk, 0, stream>>>(eWih0, w0p);
    wcvt_kernel<<<dim3(7168), blk, 0, stream>>>(eWhh0, eWih1, eWhh1, dWih0,
                                                dWhh0, dWih1, dWhh1, wsW);
    bias_kernel<<<dim3(32), blk, 0, stream>>>(ebih0, ebhh0, ebih1, ebhh1,
                                              dbih0, dbhh0, dbih1, dbhh1, bsum);
    zero16<<<dim3(256), blk, 0, stream>>>((uint4*)zstart, (int)(zeroBytes / 16));

    PP args;
    args.xp = xp; args.w0p = w0p; args.wsW = wsW; args.bsum = bsum; args.hzero = hzero;
    args.h0r = h0r; args.h1r = h1r; args.h1dec = h1dec;
    args.cnt0 = cnt0; args.cnt1 = cnt1;

    lstm_persist<<<dim3(512), blk, 73728, stream>>>(args);
    head_all<<<dim3(TAU_ * 64), blk, 0, stream>>>(h1dec, W1, b1, W2, b2, out);
}

// Round 15
// 5153.057 us; speedup vs baseline: 1.1865x; 1.1865x over previous
//
#include <hip/hip_runtime.h>
#include <math.h>

typedef _Float16 f16;
typedef __attribute__((ext_vector_type(8))) _Float16 f16x8;
typedef __attribute__((ext_vector_type(4))) _Float16 f16x4;
typedef __attribute__((ext_vector_type(4))) float f32x4;

namespace {
constexpr int B_ = 1024, T_ = 168, H_ = 512, K_ = 8, TAU_ = 24, U_ = 192;
}

__device__ __forceinline__ float sig_(float x) { return 1.0f / (1.0f + expf(-x)); }

// CPol aux bits (gfx940+): SC0=1, NT=2, SC1=16. Device scope = SC1.
template<int AUX>
__device__ __forceinline__ void gl16(const f16* g, char* l) {
    __builtin_amdgcn_global_load_lds((const __attribute__((address_space(1))) void*)g,
                                     (__attribute__((address_space(3))) void*)l, 16, 0, AUX);
}
// device-scope (LLC-coherent) 2-byte store
__device__ __forceinline__ void st_h_sc1(f16* p, f16 v) {
    unsigned int u = (unsigned int)__builtin_bit_cast(unsigned short, v);
    asm volatile("global_store_short %0, %1, off sc1" :: "v"(p), "v"(u) : "memory");
}
#define MFMA16 __builtin_amdgcn_mfma_f32_16x16x32_f16

struct PP {
    const f16 *xp, *w0p, *wsW;      // xp[t][B][64]; w0p[2048][64]; wsW: 7x[2048][512]
    const float* bsum;              // [4][2048]
    const f16* hzero;               // zeros [B][512]
    f16 *h0r, *h1r;                 // 8-deep rings of [B][512] slabs
    f16* h1dec;                     // 24 decoder h1 slabs [s][B][512]
    int *cnt0, *cnt1;               // [192][16] flag counters
};

// Persistent LSTM (r11 schedule: per step L0 -> sig -> L1 -> sig, 1 block/CU)
// with MID-PIPE dependency split: each cell stages its RECURRENT chunks first
// (dep published one step ago) and defers INPUT chunks until the serial-dep
// flag is seen via a NON-BLOCKING poll (tid0 -> LDS broadcast). The 5-chunk
// cushion of recurrent work hides the flag's LLC round-trip. h at device scope
// (sc1); weights default-cached; depth-6 pipeline; fail-soft spins.
extern "C" __global__ void __launch_bounds__(256, 1)
lstm_persist(PP P)
{
    extern __shared__ char lds[];   // 6 bufs x 24 KB + 16B flag slot
    int* flagSh = (int*)(lds + 6 * 24576);
    const int tid = threadIdx.x;
    const int id2 = (blockIdx.x & 7) * 32 + (blockIdx.x >> 3);   // XCD-chunked
    const int rt  = id2 & 15;
    const int row0 = rt * 64;
    const int j0   = (id2 >> 4) * 32;

    const int lane = tid & 63, wid = tid >> 6;
    const int l16 = lane & 15, lq = lane >> 4;
    const int wr = wid >> 1, wc = wid & 1;
    const int sr = tid >> 3, sl = tid & 7;
    const long ksw = (long)((sl ^ (sr & 7)) << 3);

    auto wgf = [&](int q) {
        const int r = sr + 32 * q;
        return (long)(((r >> 4) & 3) * H_ + j0 + ((r >> 6) << 4) + (r & 15));
    };
    const long wgr0 = wgf(0), wgr1 = wgf(1), wgr2 = wgf(2), wgr3 = wgf(3);
    const long wgH0 = wgr0 * H_ + ksw, wgH1 = wgr1 * H_ + ksw;
    const long wgH2 = wgr2 * H_ + ksw, wgH3 = wgr3 * H_ + ksw;
    const long aH0k = (long)(row0 + sr) * H_ + ksw, aH1k = aH0k + 32 * H_;

    const int swz = (l16 & 7) << 4;
    const int ab0 = (wr * 32 + l16) * 128;
    const int ab1 = ab0 + 2048;
    const int wb0 = (wc * 64 + 0 * 16 + l16) * 128, wb1 = (wc * 64 + 1 * 16 + l16) * 128;
    const int wb2 = (wc * 64 + 2 * 16 + l16) * 128, wb3 = (wc * 64 + 3 * 16 + l16) * 128;

    const size_t WM  = (size_t)2048 * 512;
    const long   NBH = (long)B_ * H_;
    bool dead = false;              // tid 0 only

    auto waitf = [&](const int* p) {
        if (tid == 0 && p && !dead) {
            int tries = 0;
            while (__hip_atomic_load(p, __ATOMIC_RELAXED,
                                     __HIP_MEMORY_SCOPE_AGENT) < 16) {
                __builtin_amdgcn_s_sleep(1);
                if (++tries > (1 << 16)) { dead = true; break; }
            }
        }
        __syncthreads();
    };
    auto sig1 = [&](int* p) {
        asm volatile("s_waitcnt vmcnt(0)" ::: "memory");
        __syncthreads();
        if (tid == 0)
            __hip_atomic_fetch_add(p, 1, __ATOMIC_RELAXED, __HIP_MEMORY_SCOPE_AGENT);
    };

    auto computeChunk = [&](char* lb, f32x4 (&acc)[4][2]) {
        #pragma unroll
        for (int ks = 0; ks < 2; ++ks) {
            const int kb = ((ks * 64) + lq * 16) ^ swz;
            f16x8 ah0 = *(const f16x8*)(lb + ab0 + kb);
            f16x8 ah1 = *(const f16x8*)(lb + ab1 + kb);
            f16x8 w0 = *(const f16x8*)(lb + 8192 + wb0 + kb);
            f16x8 w1 = *(const f16x8*)(lb + 8192 + wb1 + kb);
            f16x8 w2 = *(const f16x8*)(lb + 8192 + wb2 + kb);
            f16x8 w3 = *(const f16x8*)(lb + 8192 + wb3 + kb);
            acc[0][0] = MFMA16(ah0, w0, acc[0][0], 0, 0, 0);
            acc[0][1] = MFMA16(ah1, w0, acc[0][1], 0, 0, 0);
            acc[1][0] = MFMA16(ah0, w1, acc[1][0], 0, 0, 0);
            acc[1][1] = MFMA16(ah1, w1, acc[1][1], 0, 0, 0);
            acc[2][0] = MFMA16(ah0, w2, acc[2][0], 0, 0, 0);
            acc[2][1] = MFMA16(ah1, w2, acc[2][1], 0, 0, 0);
            acc[3][0] = MFMA16(ah0, w3, acc[3][0], 0, 0, 0);
            acc[3][1] = MFMA16(ah1, w3, acc[3][1], 0, 0, 0);
        }
    };

    auto epiF = [&](const float* bg, float* cst, f16* hout, f32x4 (&a)[4][2]) {
        const int j = j0 + wc * 16 + l16;
        const float bg0 = bg[j], bg1 = bg[H_ + j];
        const float bg2 = bg[2 * H_ + j], bg3 = bg[3 * H_ + j];
        #pragma unroll
        for (int m = 0; m < 2; ++m)
            #pragma unroll
            for (int r = 0; r < 4; ++r) {
                const int ci = m * 4 + r;
                const int bb = row0 + wr * 32 + m * 16 + lq * 4 + r;
                const long base = (long)bb * H_ + j;
                const float pi = a[0][m][r] + bg0;
                const float pf = a[1][m][r] + bg1;
                const float pg = a[2][m][r] + bg2;
                const float po = a[3][m][r] + bg3;
                const float cn = sig_(pf) * cst[ci] + sig_(pi) * tanhf(pg);
                const float hn = sig_(po) * tanhf(cn);
                cst[ci] = cn;
                st_h_sc1(&hout[base], (f16)hn);
            }
    };

    float c0st[8], c1st[8];
    #pragma unroll
    for (int i = 0; i < 8; ++i) { c0st[i] = 0.f; c1st[i] = 0.f; }

    // ---- one cell: recurrent chunks 0..7 first, input chunks 8..NC-1 after ----
    // Input staging gated on midFlag via non-blocking poll; recurrent cushion
    // keeps compute running while the flag propagates.
    auto runCell = [&](const f16* Ain, long lda, int ncIn, long Kw,
                       const f16* Wih, const f16* Hin, const f16* Whh,
                       const float* bg, float* cst, f16* hout, const int* midFlag) {
        const long aA0 = (long)(row0 + sr) * lda + ksw;
        const long aA1 = aA0 + 32 * lda;
        const long wK0 = wgr0 * Kw + ksw, wK1 = wgr1 * Kw + ksw;
        const long wK2 = wgr2 * Kw + ksw, wK3 = wgr3 * Kw + ksw;
        const int NC = ncIn + 8;
        auto st = [&](int g) {
            char* lb = lds + (g % 6) * 24576;
            const bool rc = g < 8;
            const long k0 = (long)(rc ? g : g - 8) << 6;
            const f16* Ap = rc ? Hin : Ain;
            const f16* Wp = rc ? Whh : Wih;
            gl16<16>(Ap + (rc ? aH0k : aA0) + k0, lb + tid * 16);
            gl16<16>(Ap + (rc ? aH1k : aA1) + k0, lb + 4096 + tid * 16);
            gl16<0>(Wp + (rc ? wgH0 : wK0) + k0, lb + 8192  + tid * 16);
            gl16<0>(Wp + (rc ? wgH1 : wK1) + k0, lb + 12288 + tid * 16);
            gl16<0>(Wp + (rc ? wgH2 : wK2) + k0, lb + 16384 + tid * 16);
            gl16<0>(Wp + (rc ? wgH3 : wK3) + k0, lb + 20480 + tid * 16);
        };
        f32x4 acc[4][2];
        #pragma unroll
        for (int nf = 0; nf < 4; ++nf)
            #pragma unroll
            for (int m = 0; m < 2; ++m)
                #pragma unroll
                for (int q = 0; q < 4; ++q) acc[nf][m][q] = 0.f;

        bool flagOK = (midFlag == nullptr);
        int iss = 0;
        while (iss < 5) { st(iss); ++iss; }      // prologue: rec chunks (8 >= 5)
        for (int i = 0; i < NC; ++i) {
            if (i >= iss) {                      // cushion empty: hard wait
                waitf(midFlag); flagOK = true;
                st(iss); ++iss;
            }
            // issue up to 2 chunks/iter (catch-up after a stall)
            #pragma unroll 1
            for (int b = 0; b < 2; ++b)
                if (iss < NC && (iss - i) <= 5 && (flagOK || iss < 8)) { st(iss); ++iss; }
            if (!flagOK && tid == 0)             // non-blocking poll -> LDS
                *flagSh = (__hip_atomic_load(midFlag, __ATOMIC_RELAXED,
                                             __HIP_MEMORY_SCOPE_AGENT) >= 16) ? 1 : 0;
            const int k = (iss - i - 1) > 5 ? 5 : (iss - i - 1);
            switch (k) {
                case 5: asm volatile("s_waitcnt vmcnt(30)" ::: "memory"); break;
                case 4: asm volatile("s_waitcnt vmcnt(24)" ::: "memory"); break;
                case 3: asm volatile("s_waitcnt vmcnt(18)" ::: "memory"); break;
                case 2: asm volatile("s_waitcnt vmcnt(12)" ::: "memory"); break;
                case 1: asm volatile("s_waitcnt vmcnt(6)"  ::: "memory"); break;
                default: asm volatile("s_waitcnt vmcnt(0)" ::: "memory"); break;
            }
            __builtin_amdgcn_s_barrier();        // chunk i visible; flagSh visible
            if (!flagOK) flagOK = (*flagSh != 0);
            computeChunk(lds + (i % 6) * 24576, acc);
            asm volatile("s_waitcnt lgkmcnt(0)" ::: "memory");
            __builtin_amdgcn_s_barrier();
        }
        epiF(bg, cst, hout, acc);
    };

    for (int u = 0; u < U_; ++u) {
        const bool dec = (u >= T_);
        const f16* h0prev = (u == 0) ? P.hzero : P.h0r + (long)((u - 1) & 7) * NBH;
        const f16* h1prev = (u == 0) ? P.hzero
                          : (u <= T_ ? P.h1r + (long)((u - 1) & 7) * NBH
                                     : P.h1dec + (long)(u - 1 - T_) * NBH);
        f16* h0out = P.h0r + (long)(u & 7) * NBH;

        // ---- L0(u): rec = h0(u-1) [upfront, stale flag]; input dep mid-pipe ----
        if (u > 0) waitf(P.cnt0 + (u - 1) * 16 + rt);
        if (dec) {
            // A = h1(u-1): the true serial dep -> mid-pipe flag
            runCell(h1prev, H_, 8, H_, P.wsW + 3 * WM, h0prev,
                    P.wsW + 4 * WM, P.bsum + 4096, c0st, h0out,
                    P.cnt1 + (u - 1) * 16 + rt);
        } else {
            runCell(P.xp + (long)u * B_ * 64, 64, 1, 64, P.w0p, h0prev,
                    P.wsW, P.bsum, c0st, h0out, nullptr);
        }
        sig1(P.cnt0 + u * 16 + rt);

        // ---- L1(u): rec = h1(u-1) [upfront]; A = h0(u) -> mid-pipe flag ----
        if (u > 0) waitf(P.cnt1 + (u - 1) * 16 + rt);
        f16* h1out = (u < T_) ? P.h1r + (long)(u & 7) * NBH
                              : P.h1dec + (long)(u - T_) * NBH;
        runCell(h0out, H_, 8, H_,
                dec ? P.wsW + 5 * WM : P.wsW + 1 * WM, h1prev,
                dec ? P.wsW + 6 * WM : P.wsW + 2 * WM,
                P.bsum + (dec ? 6144 : 2048), c1st, h1out,
                P.cnt0 + u * 16 + rt);
        sig1(P.cnt1 + u * 16 + rt);
    }
}

// x[B][T][32] fp32 -> xp[t][B][64] fp16 zero-padded
extern "C" __global__ void __launch_bounds__(256)
padx_kernel(const float* __restrict__ x, f16* __restrict__ xp)
{
    const int idx = blockIdx.x * 256 + threadIdx.x;     // t*B + b
    const int t = idx >> 10, b = idx & 1023;
    const float* src = x + ((long)b * T_ + t) * 32;
    f16* dst = xp + (long)idx * 64;
    #pragma unroll
    for (int q = 0; q < 8; ++q) {
        float4 v = *(const float4*)&src[q * 4];
        *(f16x4*)&dst[q * 4] = (f16x4){(f16)v.x, (f16)v.y, (f16)v.z, (f16)v.w};
    }
    #pragma unroll
    for (int q = 8; q < 16; ++q) *(f16x4*)&dst[q * 4] = (f16x4){0, 0, 0, 0};
}

// eWih0 [2048][32] fp32 -> [2048][64] fp16 zero-padded
extern "C" __global__ void __launch_bounds__(256)
padw_kernel(const float* __restrict__ w, f16* __restrict__ dst)
{
    const int idx = blockIdx.x * 256 + threadIdx.x;
    const int row = idx >> 4, k4 = idx & 15;
    f16x4 hv = (f16x4){0, 0, 0, 0};
    if (k4 < 8) {
        float4 v = *(const float4*)&w[(long)row * 32 + k4 * 4];
        hv = (f16x4){(f16)v.x, (f16)v.y, (f16)v.z, (f16)v.w};
    }
    *(f16x4*)&dst[(long)row * 64 + k4 * 4] = hv;
}

// 7 x [2048][512] fp32 -> fp16 contiguous
extern "C" __global__ void __launch_bounds__(256)
wcvt_kernel(const float* s0, const float* s1, const float* s2, const float* s3,
            const float* s4, const float* s5, const float* s6, f16* dst)
{
    const int i = blockIdx.x * 256 + threadIdx.x;
    if (i >= 7 * 262144) return;
    const int m = i >> 18, off = i & 262143;
    const float* s = m == 0 ? s0 : m == 1 ? s1 : m == 2 ? s2 : m == 3 ? s3
                   : m == 4 ? s4 : m == 5 ? s5 : s6;
    float4 v = ((const float4*)s)[off];
    *(f16x4*)&dst[(long)m * 1048576 + (long)off * 4] =
        (f16x4){(f16)v.x, (f16)v.y, (f16)v.z, (f16)v.w};
}

extern "C" __global__ void __launch_bounds__(256)
bias_kernel(const float* a0, const float* b0, const float* a1, const float* b1,
            const float* a2, const float* b2, const float* a3, const float* b3,
            float* out)   // [4][2048]: enc0, enc1, dec0, dec1
{
    const int i = blockIdx.x * 256 + threadIdx.x;
    const int l = i >> 11, k = i & 2047;
    const float* pa = l == 0 ? a0 : l == 1 ? a1 : l == 2 ? a2 : a3;
    const float* pb = l == 0 ? b0 : l == 1 ? b1 : l == 2 ? b2 : b3;
    out[i] = pa[k] + pb[k];
}

extern "C" __global__ void __launch_bounds__(256)
zero16(uint4* p, int n)
{
    for (int i = blockIdx.x * 256 + threadIdx.x; i < n; i += gridDim.x * 256)
        p[i] = make_uint4(0, 0, 0, 0);
}

// mu / sigma heads for all 24 decoder steps from h1 slabs
extern "C" __global__ void __launch_bounds__(256)
head_all(const f16* __restrict__ h1dec,
         const float* __restrict__ W1, const float* __restrict__ b1,
         const float* __restrict__ W2, const float* __restrict__ b2,
         float* __restrict__ out)
{
    const int blk = blockIdx.x;                 // 24 * 64
    const int s = blk >> 6;
    const int idx = (blk & 63) * 256 + threadIdx.x;     // 0..16383
    const int b = idx >> 4, rr = idx & 15, k = rr & 7, which = rr >> 3;
    const float* w  = (which ? W2 : W1) + (long)k * H_;
    const f16*   hp = h1dec + ((long)s * B_ + b) * H_;
    float sum = 0.f;
    for (int d = 0; d < H_; d += 8) {
        f16x8  hv = *(const f16x8*)&hp[d];
        float4 w0 = *(const float4*)&w[d];
        float4 w1 = *(const float4*)&w[d + 4];
        sum = fmaf((float)hv[0], w0.x, sum);
        sum = fmaf((float)hv[1], w0.y, sum);
        sum = fmaf((float)hv[2], w0.z, sum);
        sum = fmaf((float)hv[3], w0.w, sum);
        sum = fmaf((float)hv[4], w1.x, sum);
        sum = fmaf((float)hv[5], w1.y, sum);
        sum = fmaf((float)hv[6], w1.z, sum);
        sum = fmaf((float)hv[7], w1.w, sum);
    }
    const long o = ((long)b * TAU_ + s) * K_ + k;
    if (which == 0) {
        out[o] = sum + b1[k];
    } else {
        float z  = 2.0f * (sum + b2[k]);
        float sp = fmaxf(z, 0.0f) + log1pf(expf(-fabsf(z)));
        out[(long)B_ * TAU_ * K_ + o] = 0.5f * sp;
    }
}

extern "C" void kernel_launch(void* const* d_in, const int* in_sizes, int n_in,
                              void* d_out, int out_size, void* d_ws, size_t ws_size,
                              hipStream_t stream)
{
    (void)in_sizes; (void)n_in; (void)out_size; (void)ws_size;

    const float* x     = (const float*)d_in[0];
    const float* eWih0 = (const float*)d_in[1];
    const float* eWhh0 = (const float*)d_in[2];
    const float* ebih0 = (const float*)d_in[3];
    const float* ebhh0 = (const float*)d_in[4];
    const float* eWih1 = (const float*)d_in[5];
    const float* eWhh1 = (const float*)d_in[6];
    const float* ebih1 = (const float*)d_in[7];
    const float* ebhh1 = (const float*)d_in[8];
    const float* dWih0 = (const float*)d_in[9];
    const float* dWhh0 = (const float*)d_in[10];
    const float* dbih0 = (const float*)d_in[11];
    const float* dbhh0 = (const float*)d_in[12];
    const float* dWih1 = (const float*)d_in[13];
    const float* dWhh1 = (const float*)d_in[14];
    const float* dbih1 = (const float*)d_in[15];
    const float* dbhh1 = (const float*)d_in[16];
    const float* W1    = (const float*)d_in[17];
    const float* b1    = (const float*)d_in[18];
    const float* W2    = (const float*)d_in[19];
    const float* b2    = (const float*)d_in[20];
    float* out = (float*)d_out;

    (void)hipFuncSetAttribute((const void*)lstm_persist,
                              hipFuncAttributeMaxDynamicSharedMemorySize, 147472);

    char* wsp = (char*)d_ws;
    auto take = [&](size_t n) { void* p = (void*)wsp; wsp += n; return p; };

    f16* xp    = (f16*)take((size_t)T_ * B_ * 64 * 2);
    f16* w0p   = (f16*)take((size_t)2048 * 64 * 2);
    f16* wsW   = (f16*)take((size_t)7 * 2048 * 512 * 2);
    float* bsum = (float*)take((size_t)4 * 2048 * 4);
    f16* h1dec = (f16*)take((size_t)TAU_ * B_ * H_ * 2);
    f16* h0r   = (f16*)take((size_t)8 * B_ * H_ * 2);
    f16* h1r   = (f16*)take((size_t)8 * B_ * H_ * 2);

    char* zstart = wsp;
    int* cnt0  = (int*)take((size_t)U_ * 16 * 4);
    int* cnt1  = (int*)take((size_t)U_ * 16 * 4);
    f16* hzero = (f16*)take((size_t)B_ * H_ * 2);
    const size_t zeroBytes = (size_t)(wsp - zstart);

    const dim3 blk(256);

    padx_kernel<<<dim3(T_ * B_ / 256), blk, 0, stream>>>(x, xp);
    padw_kernel<<<dim3(128), blk, 0, stream>>>(eWih0, w0p);
    wcvt_kernel<<<dim3(7168), blk, 0, stream>>>(eWhh0, eWih1, eWhh1, dWih0,
                                                dWhh0, dWih1, dWhh1, wsW);
    bias_kernel<<<dim3(32), blk, 0, stream>>>(ebih0, ebhh0, ebih1, ebhh1,
                                              dbih0, dbhh0, dbih1, dbhh1, bsum);
    zero16<<<dim3(256), blk, 0, stream>>>((uint4*)zstart, (int)(zeroBytes / 16));

    PP args;
    args.xp = xp; args.w0p = w0p; args.wsW = wsW; args.bsum = bsum; args.hzero = hzero;
    args.h0r = h0r; args.h1r = h1r; args.h1dec = h1dec;
    args.cnt0 = cnt0; args.cnt1 = cnt1;

    lstm_persist<<<dim3(256), blk, 147472, stream>>>(args);
    head_all<<<dim3(TAU_ * 64), blk, 0, stream>>>(h1dec, W1, b1, W2, b2, out);
}